// Round 13
// baseline (198.623 us; speedup 1.0000x reference)
//
#include <hip/hip_runtime.h>
#include <hip/hip_fp16.h>

constexpr int N_NODES = 100000;
constexpr int N_EDGES = 1600000;
constexpr int D = 64;

// ---- coarse bucket parameters (fast path, round-7 proven) ----
constexpr int SHC    = 9;                                  // 512 nodes / coarse bucket
constexpr int BSZC   = 1 << SHC;                           // 512
constexpr int NBC    = (N_NODES + BSZC - 1) / BSZC;        // 196 coarse buckets
constexpr int SPLITB = 256;                                // hist tiles (K1)
constexpr int TILE   = (N_EDGES + SPLITB - 1) / SPLITB;    // 6250 edges / hist tile
constexpr int CVB    = 1024;                               // convert blocks in fused front
constexpr int TILE2  = 8192;                               // scatter tile (8 e/thr @1024)
constexpr int NBLK2  = (N_EDGES + TILE2 - 1) / TILE2;      // 196 scatter blocks

// ---- mid-tier (proven) scan parameters ----
constexpr int SCAN_CHUNK = 1024;
constexpr int NCHUNK = (N_NODES + SCAN_CHUNK - 1) / SCAN_CHUNK;   // 98

__device__ __forceinline__ int waveInclScan(int v, int lane) {
    #pragma unroll
    for (int off = 1; off < 64; off <<= 1) {
        int t = __shfl_up(v, off, 64);
        if (lane >= off) v += t;
    }
    return v;
}

// ---------------------------------------------------------------------------
// K1 fused front: blocks [0,CVB) cast vertices fp32 -> Xh fp16 (pure stream;
// the matmul is GONE — by linearity agg(X)@W^T = agg(X@W^T), so the matvec
// moves into the gather epilogue). Blocks [CVB,CVB+SPLITB) histogram their
// edge tile into LDS -> bcntC (round-7 proven).
// ---------------------------------------------------------------------------
__global__ __launch_bounds__(256) void cvt_hist(
    const float* __restrict__ vertices,
    __half* __restrict__ Xh,
    const int* __restrict__ edges,
    int* __restrict__ bcntC)
{
    if (blockIdx.x < CVB) {
        const int total8 = N_NODES * D / 8;               // 800000 groups of 8
        const float4* v4 = reinterpret_cast<const float4*>(vertices);
        for (int i = blockIdx.x * 256 + threadIdx.x; i < total8; i += CVB * 256) {
            float4 f0 = v4[2 * i];
            float4 f1 = v4[2 * i + 1];
            __half2 h01 = __floats2half2_rn(f0.x, f0.y);
            __half2 h23 = __floats2half2_rn(f0.z, f0.w);
            __half2 h45 = __floats2half2_rn(f1.x, f1.y);
            __half2 h67 = __floats2half2_rn(f1.z, f1.w);
            uint4 u;
            u.x = *reinterpret_cast<const unsigned*>(&h01);
            u.y = *reinterpret_cast<const unsigned*>(&h23);
            u.z = *reinterpret_cast<const unsigned*>(&h45);
            u.w = *reinterpret_cast<const unsigned*>(&h67);
            *reinterpret_cast<uint4*>(Xh + (size_t)i * 8) = u;
        }
    } else {
        __shared__ int h[NBC];
        const int b = blockIdx.x - CVB;
        if (threadIdx.x < NBC) h[threadIdx.x] = 0;
        __syncthreads();
        const int lo = b * TILE;
        const int hi = min(lo + TILE, N_EDGES);
        for (int e = lo + threadIdx.x; e < hi; e += 256)
            atomicAdd(&h[edges[e] >> SHC], 1);
        __syncthreads();
        if (threadIdx.x < NBC) {
            int v = h[threadIdx.x];
            if (v) atomicAdd(&bcntC[threadIdx.x], v);
        }
    }
}

// ---------------------------------------------------------------------------
// K2 reservation scatter (round-7 proven): 196 blocks x 1024 thr, 8 e/thread.
// ---------------------------------------------------------------------------
__global__ __launch_bounds__(1024) void s_scatter(const int* __restrict__ edges,
                                                  const int* __restrict__ bcntC,
                                                  int* __restrict__ cursorDelta,
                                                  int* __restrict__ bbaseC,
                                                  int* __restrict__ packed)
{
    __shared__ int s[256];
    __shared__ int baseC[NBC];
    __shared__ int h[NBC];
    __shared__ int chunk[NBC];
    const int t = threadIdx.x;

    int v = 0;
    if (t < 256) { v = (t < NBC) ? bcntC[t] : 0; s[t] = v; }
    __syncthreads();
    for (int o = 1; o < 256; o <<= 1) {
        int u = (t < 256 && t >= o) ? s[t - o] : 0;
        __syncthreads();
        if (t < 256) s[t] += u;
        __syncthreads();
    }
    if (t < NBC) {
        int e = s[t] - v;
        baseC[t] = e;
        h[t] = 0;
        if (blockIdx.x == 0) bbaseC[t] = e;
    }
    __syncthreads();

    const int lo = blockIdx.x * TILE2;
    int myd[8];
    #pragma unroll
    for (int k = 0; k < 8; ++k) {
        int e = lo + k * 1024 + t;
        myd[k] = (e < N_EDGES) ? edges[e] : -1;
        if (myd[k] >= 0) atomicAdd(&h[myd[k] >> SHC], 1);
    }
    __syncthreads();

    if (t < NBC) {
        int c = h[t];
        chunk[t] = c ? (baseC[t] + atomicAdd(&cursorDelta[t], c)) : 0;
        h[t] = 0;                        // reuse as local cursor
    }
    __syncthreads();

    #pragma unroll
    for (int k = 0; k < 8; ++k) {
        if (myd[k] >= 0) {
            int e = lo + k * 1024 + t;
            int src = edges[N_EDGES + e];
            int j = myd[k] >> SHC;
            int r = atomicAdd(&h[j], 1);
            packed[chunk[j] + r] = (src << SHC) | (myd[k] & (BSZC - 1));
        }
    }
}

// ---------------------------------------------------------------------------
// K3 csr512 (round-12): one block per coarse region (196 x 1024 thr),
// packed register-cached so it's read ~once.
// ---------------------------------------------------------------------------
__global__ __launch_bounds__(1024) void csr512(const int* __restrict__ packed,
                                               const int* __restrict__ bbaseC,
                                               const int* __restrict__ bcntC,
                                               int* __restrict__ offsets,
                                               int* __restrict__ deg,
                                               int* __restrict__ srt)
{
    __shared__ int h2[BSZC];
    __shared__ int cur2[BSZC];
    __shared__ int s[BSZC];
    const int b = blockIdx.x;
    const int t = threadIdx.x;
    const int start = bbaseC[b];
    const int cnt   = bcntC[b];

    if (t < BSZC) h2[t] = 0;
    __syncthreads();

    int myp[8];
    #pragma unroll
    for (int k = 0; k < 8; ++k) {
        int i = k * 1024 + t;
        myp[k] = (i < cnt) ? packed[start + i] : -1;
        if (myp[k] >= 0) atomicAdd(&h2[myp[k] & (BSZC - 1)], 1);
    }
    for (int i = 8192 + t; i < cnt; i += 1024)     // rare remainder
        atomicAdd(&h2[packed[start + i] & (BSZC - 1)], 1);
    __syncthreads();

    if (t < BSZC) s[t] = h2[t];
    __syncthreads();
    for (int o = 1; o < BSZC; o <<= 1) {
        int u = (t < BSZC && t >= o) ? s[t - o] : 0;
        __syncthreads();
        if (t < BSZC) s[t] += u;
        __syncthreads();
    }
    if (t < BSZC) {
        int excl = s[t] - h2[t];
        int node = (b << SHC) + t;
        if (node < N_NODES) { offsets[node] = start + excl; deg[node] = h2[t]; }
        cur2[t] = excl;
    }
    __syncthreads();

    #pragma unroll
    for (int k = 0; k < 8; ++k) {
        if (myp[k] >= 0) {
            int r = atomicAdd(&cur2[myp[k] & (BSZC - 1)], 1);
            srt[start + r] = myp[k] >> SHC;
        }
    }
    for (int i = 8192 + t; i < cnt; i += 1024) {   // rare remainder
        int p = packed[start + i];
        int r = atomicAdd(&cur2[p & (BSZC - 1)], 1);
        srt[start + r] = p >> SHC;
    }
}

// ---------------------------------------------------------------------------
// K4 gather_lin: round-10 proven gather structure on Xh (raw fp16 vertices),
// two nodes per wave, PLUS fused epilogue matvec: agg (scaled) -> LDS strip,
// lane j computes out[n][j] = sum_f agg[f]*W[j][f] with W row in registers
// (loaded AFTER the gather loop; launch_bounds min-waves=2 for the budget).
// Grid is exactly 12500 blocks x 8 nodes = 100000 -> no partial blocks.
// ---------------------------------------------------------------------------
__device__ __forceinline__ void addrow(float* acc, uint4 u)
{
    const __half2* h = reinterpret_cast<const __half2*>(&u);
    #pragma unroll
    for (int k = 0; k < 4; ++k) {
        float2 f = __half22float2(h[k]);
        acc[2 * k]     += f.x;
        acc[2 * k + 1] += f.y;
    }
}

__global__ __launch_bounds__(256, 2) void gather_lin(
    const __half* __restrict__ Xh,
    const int* __restrict__ offsets,
    const int* __restrict__ deg,
    const int* __restrict__ srt,
    const float* __restrict__ weight,   // [64][64] row-major
    const float* __restrict__ bias,
    float* __restrict__ out)
{
    __shared__ __align__(16) float aggbuf[8][64];

    const int wid  = threadIdx.x >> 6;
    const int lane = threadIdx.x & 63;
    const int g    = lane >> 3;          // edge slot within octet
    const int sub  = lane & 7;           // 16B chunk within 128B row
    const int n0   = blockIdx.x * 8 + wid * 2;
    const int n1   = n0 + 1;
    if (n0 >= N_NODES) return;           // never true (exact grid); wave-uniform
    const bool has1 = (n1 < N_NODES);

    const int st0 = offsets[n0];
    const int c0  = deg[n0];
    int st1 = 0, c1 = 0;
    if (has1) { st1 = offsets[n1]; c1 = deg[n1]; }

    float a0[8], a1[8];
    #pragma unroll
    for (int j = 0; j < 8; ++j) { a0[j] = 0.0f; a1[j] = 0.0f; }

    if (g == 0) {                        // self loops
        uint4 u0 = *reinterpret_cast<const uint4*>(Xh + (size_t)n0 * D + sub * 8);
        addrow(a0, u0);
        if (has1) {
            uint4 u1 = *reinterpret_cast<const uint4*>(Xh + (size_t)n1 * D + sub * 8);
            addrow(a1, u1);
        }
    }

    // interleaved main: one row-load per node per step -> 2+ loads in flight
    const int m = min(c0 & ~7, c1 & ~7);
    int e = 0;
    for (; e < m; e += 8) {
        int s0 = srt[st0 + e + g];
        int s1 = srt[st1 + e + g];
        uint4 u0 = *reinterpret_cast<const uint4*>(Xh + (size_t)s0 * D + sub * 8);
        uint4 u1 = *reinterpret_cast<const uint4*>(Xh + (size_t)s1 * D + sub * 8);
        addrow(a0, u0);
        addrow(a1, u1);
    }

    // drain node0
    int e0 = e;
    for (; e0 + 16 <= c0; e0 += 16) {
        int s0 = srt[st0 + e0 + g];
        int s1 = srt[st0 + e0 + 8 + g];
        uint4 u0 = *reinterpret_cast<const uint4*>(Xh + (size_t)s0 * D + sub * 8);
        uint4 u1 = *reinterpret_cast<const uint4*>(Xh + (size_t)s1 * D + sub * 8);
        addrow(a0, u0);
        addrow(a0, u1);
    }
    if (e0 + 8 <= c0) {
        int s0 = srt[st0 + e0 + g];
        uint4 u0 = *reinterpret_cast<const uint4*>(Xh + (size_t)s0 * D + sub * 8);
        addrow(a0, u0);
        e0 += 8;
    }
    if (e0 + g < c0) {
        int s0 = srt[st0 + e0 + g];
        uint4 u0 = *reinterpret_cast<const uint4*>(Xh + (size_t)s0 * D + sub * 8);
        addrow(a0, u0);
    }

    // drain node1
    if (has1) {
        int e1 = e;
        for (; e1 + 16 <= c1; e1 += 16) {
            int s0 = srt[st1 + e1 + g];
            int s1 = srt[st1 + e1 + 8 + g];
            uint4 u0 = *reinterpret_cast<const uint4*>(Xh + (size_t)s0 * D + sub * 8);
            uint4 u1 = *reinterpret_cast<const uint4*>(Xh + (size_t)s1 * D + sub * 8);
            addrow(a1, u0);
            addrow(a1, u1);
        }
        if (e1 + 8 <= c1) {
            int s0 = srt[st1 + e1 + g];
            uint4 u0 = *reinterpret_cast<const uint4*>(Xh + (size_t)s0 * D + sub * 8);
            addrow(a1, u0);
            e1 += 8;
        }
        if (e1 + g < c1) {
            int s0 = srt[st1 + e1 + g];
            uint4 u0 = *reinterpret_cast<const uint4*>(Xh + (size_t)s0 * D + sub * 8);
            addrow(a1, u0);
        }
    }

    #pragma unroll
    for (int j = 0; j < 8; ++j) {
        a0[j] += __shfl_xor(a0[j], 8, 64);
        a0[j] += __shfl_xor(a0[j], 16, 64);
        a0[j] += __shfl_xor(a0[j], 32, 64);
        a1[j] += __shfl_xor(a1[j], 8, 64);
        a1[j] += __shfl_xor(a1[j], 16, 64);
        a1[j] += __shfl_xor(a1[j], 32, 64);
    }

    // stage scaled agg rows to the per-wave LDS strip
    if (g == 0) {
        {
            const float sc = rsqrtf((float)c0 + 1.0f);
            float4 q0, q1;
            q0.x = a0[0] * sc; q0.y = a0[1] * sc; q0.z = a0[2] * sc; q0.w = a0[3] * sc;
            q1.x = a0[4] * sc; q1.y = a0[5] * sc; q1.z = a0[6] * sc; q1.w = a0[7] * sc;
            *reinterpret_cast<float4*>(&aggbuf[wid * 2][sub * 8])     = q0;
            *reinterpret_cast<float4*>(&aggbuf[wid * 2][sub * 8 + 4]) = q1;
        }
        if (has1) {
            const float sc = rsqrtf((float)c1 + 1.0f);
            float4 q0, q1;
            q0.x = a1[0] * sc; q0.y = a1[1] * sc; q0.z = a1[2] * sc; q0.w = a1[3] * sc;
            q1.x = a1[4] * sc; q1.y = a1[5] * sc; q1.z = a1[6] * sc; q1.w = a1[7] * sc;
            *reinterpret_cast<float4*>(&aggbuf[wid * 2 + 1][sub * 8])     = q0;
            *reinterpret_cast<float4*>(&aggbuf[wid * 2 + 1][sub * 8 + 4]) = q1;
        }
    }
    __syncthreads();

    // fused matvec: lane j owns output feature j for this wave's two nodes.
    // Load W row AFTER the gather loop (keeps main-loop liveness small).
    float4 w4[16];
    const float4* wrow = reinterpret_cast<const float4*>(weight + (size_t)lane * 64);
    #pragma unroll
    for (int f4 = 0; f4 < 16; ++f4) w4[f4] = wrow[f4];
    const float b = bias[lane];

    const float4* r0 = reinterpret_cast<const float4*>(&aggbuf[wid * 2][0]);
    const float4* r1 = reinterpret_cast<const float4*>(&aggbuf[wid * 2 + 1][0]);
    float y0 = 0.0f, y1 = 0.0f;
    #pragma unroll
    for (int f4 = 0; f4 < 16; ++f4) {
        float4 q0 = r0[f4];
        float4 q1 = r1[f4];
        y0 += q0.x * w4[f4].x + q0.y * w4[f4].y + q0.z * w4[f4].z + q0.w * w4[f4].w;
        y1 += q1.x * w4[f4].x + q1.y * w4[f4].y + q1.z * w4[f4].z + q1.w * w4[f4].w;
    }
    out[(size_t)n0 * D + lane] = y0 + b;
    if (has1) out[(size_t)n1 * D + lane] = y1 + b;
}

// ---------------------------------------------------------------------------
// mid tier: round-0 proven pipeline (fp32 throughout)
// ---------------------------------------------------------------------------

__global__ __launch_bounds__(256) void linear_kernel(
    const float* __restrict__ vertices,
    const float* __restrict__ weight,
    float* __restrict__ Y)
{
    __shared__ float rowbuf[4][64];
    const int wid  = threadIdx.x >> 6;
    const int lane = threadIdx.x & 63;
    float w[64];
    #pragma unroll
    for (int f = 0; f < 64; ++f) w[f] = weight[lane * 64 + f];
    const int nodesPerIter = gridDim.x * 4;
    for (int base = blockIdx.x * 4; base < N_NODES; base += nodesPerIter) {
        const int node = base + wid;
        float a = 0.0f;
        if (node < N_NODES) a = vertices[(size_t)node * D + lane];
        rowbuf[wid][lane] = a;
        __syncthreads();
        float acc = 0.0f;
        #pragma unroll
        for (int f = 0; f < 64; ++f)
            acc += rowbuf[wid][f] * w[f];
        if (node < N_NODES) Y[(size_t)node * D + lane] = acc;
        __syncthreads();
    }
}

__global__ __launch_bounds__(256) void gather_f32(
    const float* __restrict__ Y,
    const int* __restrict__ offsets,
    const int* __restrict__ deg,
    const int* __restrict__ sortedSrc,
    const float* __restrict__ bias,
    float* __restrict__ out)
{
    const int wid  = threadIdx.x >> 6;
    const int lane = threadIdx.x & 63;
    const int g    = lane >> 4;
    const int sub  = lane & 15;
    const int node = blockIdx.x * 4 + wid;
    if (node >= N_NODES) return;

    const int start = offsets[node];
    const int cnt   = deg[node];

    float4 acc;
    if (g == 0) {
        acc = *reinterpret_cast<const float4*>(Y + (size_t)node * D + (sub << 2));
    } else {
        acc.x = 0.0f; acc.y = 0.0f; acc.z = 0.0f; acc.w = 0.0f;
    }

    int e = 0;
    for (; e + 8 <= cnt; e += 8) {
        int s0 = sortedSrc[start + e + g];
        int s1 = sortedSrc[start + e + 4 + g];
        const float4 a0 = *reinterpret_cast<const float4*>(Y + (size_t)s0 * D + (sub << 2));
        const float4 a1 = *reinterpret_cast<const float4*>(Y + (size_t)s1 * D + (sub << 2));
        acc.x += a0.x; acc.y += a0.y; acc.z += a0.z; acc.w += a0.w;
        acc.x += a1.x; acc.y += a1.y; acc.z += a1.z; acc.w += a1.w;
    }
    if (e + 4 <= cnt) {
        int s0 = sortedSrc[start + e + g];
        const float4 a0 = *reinterpret_cast<const float4*>(Y + (size_t)s0 * D + (sub << 2));
        acc.x += a0.x; acc.y += a0.y; acc.z += a0.z; acc.w += a0.w;
        e += 4;
    }
    if (e + g < cnt) {
        int s0 = sortedSrc[start + e + g];
        const float4 a0 = *reinterpret_cast<const float4*>(Y + (size_t)s0 * D + (sub << 2));
        acc.x += a0.x; acc.y += a0.y; acc.z += a0.z; acc.w += a0.w;
    }

    acc.x += __shfl_xor(acc.x, 16, 64);
    acc.y += __shfl_xor(acc.y, 16, 64);
    acc.z += __shfl_xor(acc.z, 16, 64);
    acc.w += __shfl_xor(acc.w, 16, 64);
    acc.x += __shfl_xor(acc.x, 32, 64);
    acc.y += __shfl_xor(acc.y, 32, 64);
    acc.z += __shfl_xor(acc.z, 32, 64);
    acc.w += __shfl_xor(acc.w, 32, 64);

    if (lane < 16) {
        const float sc = rsqrtf((float)cnt + 1.0f);
        const float4 b4 = *reinterpret_cast<const float4*>(bias + (sub << 2));
        float4 r;
        r.x = acc.x * sc + b4.x;
        r.y = acc.y * sc + b4.y;
        r.z = acc.z * sc + b4.z;
        r.w = acc.w * sc + b4.w;
        *reinterpret_cast<float4*>(out + (size_t)node * D + (sub << 2)) = r;
    }
}

__global__ __launch_bounds__(256) void hist_kernel(const int* __restrict__ edges,
                                                   int* __restrict__ deg)
{
    int e = blockIdx.x * 256 + threadIdx.x;
    if (e < N_EDGES) atomicAdd(&deg[edges[e]], 1);
}

__global__ __launch_bounds__(256) void scan_part(const int* __restrict__ deg,
                                                 int* __restrict__ partial)
{
    int t = threadIdx.x;
    int base = blockIdx.x * SCAN_CHUNK + t * 4;
    int s = 0;
    #pragma unroll
    for (int k = 0; k < 4; ++k) { int i = base + k; if (i < N_NODES) s += deg[i]; }
    int lane = t & 63, wid = t >> 6;
    #pragma unroll
    for (int off = 32; off; off >>= 1) s += __shfl_down(s, off, 64);
    __shared__ int red[4];
    if (lane == 0) red[wid] = s;
    __syncthreads();
    if (t == 0) partial[blockIdx.x] = red[0] + red[1] + red[2] + red[3];
}

__global__ void scan_small(int* partial) {
    int lane = threadIdx.x;
    int v0 = (lane < NCHUNK) ? partial[lane] : 0;
    int v1 = (64 + lane < NCHUNK) ? partial[64 + lane] : 0;
    int i0 = waveInclScan(v0, lane);
    int tot0 = __shfl(i0, 63, 64);
    int i1 = waveInclScan(v1, lane) + tot0;
    if (lane < NCHUNK) partial[lane] = i0 - v0;
    if (64 + lane < NCHUNK) partial[64 + lane] = i1 - v1;
}

__global__ __launch_bounds__(256) void scan_final(const int* __restrict__ deg,
                                                  const int* __restrict__ partial,
                                                  int* __restrict__ offsets,
                                                  int* __restrict__ cursor)
{
    int t = threadIdx.x;
    int base = blockIdx.x * SCAN_CHUNK + t * 4;
    int d[4]; int s = 0;
    #pragma unroll
    for (int k = 0; k < 4; ++k) { int i = base + k; d[k] = (i < N_NODES) ? deg[i] : 0; s += d[k]; }
    __shared__ int sd[256];
    sd[t] = s; __syncthreads();
    #pragma unroll
    for (int off = 1; off < 256; off <<= 1) {
        int v = (t >= off) ? sd[t - off] : 0;
        __syncthreads();
        sd[t] += v;
        __syncthreads();
    }
    int excl = sd[t] - s + partial[blockIdx.x];
    #pragma unroll
    for (int k = 0; k < 4; ++k) {
        int i = base + k;
        if (i < N_NODES) { offsets[i] = excl; cursor[i] = excl; excl += d[k]; }
    }
}

__global__ __launch_bounds__(256) void scatter_idx(const int* __restrict__ edges,
                                                   int* __restrict__ cursor,
                                                   int* __restrict__ sortedSrc)
{
    int e = blockIdx.x * 256 + threadIdx.x;
    if (e >= N_EDGES) return;
    int dst = edges[e];
    int src = edges[N_EDGES + e];
    int pos = atomicAdd(&cursor[dst], 1);
    sortedSrc[pos] = src;
}

// ---------------------------------------------------------------------------
// last-resort fallback (round-1, proven)
// ---------------------------------------------------------------------------

__global__ __launch_bounds__(256) void fb_scatter(
    const float* __restrict__ vertices, const int* __restrict__ edges,
    float* __restrict__ agg, float* __restrict__ degF)
{
    long long tid = (long long)blockIdx.x * 256 + threadIdx.x;
    int lane = threadIdx.x & 63;
    long long e = tid >> 6;
    if (e >= N_EDGES) return;
    int dst = edges[e];
    int src = edges[N_EDGES + e];
    atomicAdd(&agg[(size_t)dst * D + lane], vertices[(size_t)src * D + lane]);
    if (lane == 0) atomicAdd(&degF[dst], 1.0f);
}

__global__ __launch_bounds__(256) void fb_finish(
    const float* __restrict__ vertices, const float* __restrict__ weight,
    const float* __restrict__ bias, const float* __restrict__ degF,
    float* __restrict__ out)
{
    __shared__ float rowbuf[4][64];
    const int wid  = threadIdx.x >> 6;
    const int lane = threadIdx.x & 63;
    float w[64];
    #pragma unroll
    for (int f = 0; f < 64; ++f) w[f] = weight[lane * 64 + f];
    const float b = bias[lane];
    const int nodesPerIter = gridDim.x * 4;
    for (int base = blockIdx.x * 4; base < N_NODES; base += nodesPerIter) {
        const int node = base + wid;
        float a = 0.0f;
        if (node < N_NODES) {
            const float scale = rsqrtf(degF[node] + 1.0f);
            a = (out[(size_t)node * D + lane] + vertices[(size_t)node * D + lane]) * scale;
        }
        rowbuf[wid][lane] = a;
        __syncthreads();
        float acc = b;
        #pragma unroll
        for (int f = 0; f < 64; ++f) acc += rowbuf[wid][f] * w[f];
        if (node < N_NODES) out[(size_t)node * D + lane] = acc;
        __syncthreads();
    }
}

extern "C" void kernel_launch(void* const* d_in, const int* in_sizes, int n_in,
                              void* d_out, int out_size, void* d_ws, size_t ws_size,
                              hipStream_t stream) {
    const float* vertices = (const float*)d_in[0];
    const int*   edges    = (const int*)d_in[1];
    const float* weight   = (const float*)d_in[2];
    const float* bias     = (const float*)d_in[3];
    float* out = (float*)d_out;

    const int threads = 256;
    const int edgeBlocks = (N_EDGES + threads - 1) / threads;

    // --- fast layout: Xh(fp16) | bcntC | cursorDelta | bbaseC | offs | deg | packed | srt
    {
        __half* Xh         = (__half*)d_ws;
        int*   bcntC       = (int*)(Xh + (size_t)N_NODES * D);
        int*   cursorDelta = bcntC + NBC;
        int*   bbaseC      = cursorDelta + NBC;
        int*   offs        = bbaseC + NBC;
        int*   deg         = offs + N_NODES;
        int*   packed      = deg + N_NODES;
        int*   srt         = packed + N_EDGES;
        size_t needed      = (size_t)((char*)(srt + N_EDGES) - (char*)d_ws);
        if (ws_size >= needed) {
            (void)hipMemsetAsync(bcntC, 0, sizeof(int) * 2 * NBC, stream);  // bcntC + cursorDelta
            cvt_hist<<<CVB + SPLITB, threads, 0, stream>>>(vertices, Xh, edges, bcntC);
            s_scatter<<<NBLK2, 1024, 0, stream>>>(edges, bcntC, cursorDelta, bbaseC, packed);
            csr512<<<NBC, 1024, 0, stream>>>(packed, bbaseC, bcntC, offs, deg, srt);
            gather_lin<<<(N_NODES + 7) / 8, threads, 0, stream>>>(Xh, offs, deg, srt, weight, bias, out);
            return;
        }
    }

    // --- mid layout (round-0 proven): Y | deg | offsets | cursor | partial[128] | srt
    {
        float* Y       = (float*)d_ws;
        int*   deg     = (int*)(Y + (size_t)N_NODES * D);
        int*   offs    = deg + N_NODES;
        int*   cursor  = offs + N_NODES;
        int*   partial = cursor + N_NODES;
        int*   srt     = partial + 128;
        size_t needed  = (size_t)((char*)(srt + N_EDGES) - (char*)d_ws);
        if (ws_size >= needed) {
            (void)hipMemsetAsync(deg, 0, sizeof(int) * N_NODES, stream);
            linear_kernel<<<1024, threads, 0, stream>>>(vertices, weight, Y);
            hist_kernel<<<edgeBlocks, threads, 0, stream>>>(edges, deg);
            scan_part<<<NCHUNK, threads, 0, stream>>>(deg, partial);
            scan_small<<<1, 64, 0, stream>>>(partial);
            scan_final<<<NCHUNK, threads, 0, stream>>>(deg, partial, offs, cursor);
            scatter_idx<<<edgeBlocks, threads, 0, stream>>>(edges, cursor, srt);
            gather_f32<<<(N_NODES + 3) / 4, threads, 0, stream>>>(Y, offs, deg, srt, bias, out);
            return;
        }
    }

    // --- last resort
    {
        float* degF = (float*)d_ws;
        (void)hipMemsetAsync(out, 0, sizeof(float) * (size_t)N_NODES * D, stream);
        (void)hipMemsetAsync(degF, 0, sizeof(float) * N_NODES, stream);
        const long long totalScatter = (long long)N_EDGES * 64;
        fb_scatter<<<(int)((totalScatter + threads - 1) / threads), threads, 0, stream>>>(
            vertices, edges, out, degF);
        fb_finish<<<1024, threads, 0, stream>>>(vertices, weight, bias, degF, out);
    }
}

// Round 14
// 107.525 us; speedup vs baseline: 1.8472x; 1.8472x over previous
//
#include <hip/hip_runtime.h>
#include <hip/hip_fp16.h>

constexpr int N_NODES = 100000;
constexpr int N_EDGES = 1600000;
constexpr int D = 64;

typedef _Float16 half8 __attribute__((ext_vector_type(8)));
typedef float floatx4 __attribute__((ext_vector_type(4)));

// ---- coarse bucket parameters (fast path, round-7 proven) ----
constexpr int SHC    = 9;                                  // 512 nodes / coarse bucket
constexpr int BSZC   = 1 << SHC;                           // 512
constexpr int NBC    = (N_NODES + BSZC - 1) / BSZC;        // 196 coarse buckets
constexpr int SPLITB = 256;                                // hist tiles (K1)
constexpr int TILE   = (N_EDGES + SPLITB - 1) / SPLITB;    // 6250 edges / hist tile
constexpr int NTILES = N_NODES / 16;                       // 6250 MFMA node-tiles (exact)
constexpr int MFB    = (NTILES + 3) / 4;                   // 1563 linear blocks (4 waves)
constexpr int TILE2  = 8192;                               // scatter tile (8 e/thr @1024)
constexpr int NBLK2  = (N_EDGES + TILE2 - 1) / TILE2;      // 196 scatter blocks

// ---- mid-tier (proven) scan parameters ----
constexpr int SCAN_CHUNK = 1024;
constexpr int NCHUNK = (N_NODES + SCAN_CHUNK - 1) / SCAN_CHUNK;   // 98

__device__ __forceinline__ int waveInclScan(int v, int lane) {
    #pragma unroll
    for (int off = 1; off < 64; off <<= 1) {
        int t = __shfl_up(v, off, 64);
        if (lane >= off) v += t;
    }
    return v;
}

// ---------------------------------------------------------------------------
// K1 fused front: blocks [0,MFB) compute Yh = fp16(X @ W^T) via MFMA
// (one 16-node x 64-feature tile per wave; 8x mfma_f32_16x16x32_f16).
// Layouts: A lane l: row=l&15, k=(l>>4)*8+e; B lane l: col=l&15, k=(l>>4)*8+e
// (so B[k][j] = W[j][k]); D lane l reg r: node=(l>>4)*4+r, feat=l&15 (+16*jg).
// Blocks [MFB,MFB+SPLITB) histogram their edge tile into LDS -> bcntC.
// ---------------------------------------------------------------------------
__global__ __launch_bounds__(256) void mfma_hist(
    const float* __restrict__ vertices,
    const float* __restrict__ weight,   // [64][64] row-major
    __half* __restrict__ Yh,
    const int* __restrict__ edges,
    int* __restrict__ bcntC)
{
    if (blockIdx.x < MFB) {
        const int wid  = threadIdx.x >> 6;
        const int lane = threadIdx.x & 63;
        const int tile = blockIdx.x * 4 + wid;
        if (tile >= NTILES) return;      // wave-uniform (last block only)

        const int row16 = lane & 15;     // A row / B col within tile
        const int kgrp  = lane >> 4;     // k-subgroup (0..3), 8 elems each

        // B fragments: W[jg*16+row16][c*32 + kgrp*8 + e], fp32 -> f16
        half8 bfrag[2][4];
        #pragma unroll
        for (int c = 0; c < 2; ++c) {
            #pragma unroll
            for (int jg = 0; jg < 4; ++jg) {
                const float* wp = weight + (size_t)(jg * 16 + row16) * 64 + c * 32 + kgrp * 8;
                float4 w0 = *reinterpret_cast<const float4*>(wp);
                float4 w1 = *reinterpret_cast<const float4*>(wp + 4);
                half8 h;
                h[0] = (_Float16)w0.x; h[1] = (_Float16)w0.y;
                h[2] = (_Float16)w0.z; h[3] = (_Float16)w0.w;
                h[4] = (_Float16)w1.x; h[5] = (_Float16)w1.y;
                h[6] = (_Float16)w1.z; h[7] = (_Float16)w1.w;
                bfrag[c][jg] = h;
            }
        }

        const int base = tile * 16;
        // A fragments: X[base+row16][c*32 + kgrp*8 + e]
        half8 afrag[2];
        #pragma unroll
        for (int c = 0; c < 2; ++c) {
            const float* xp = vertices + (size_t)(base + row16) * 64 + c * 32 + kgrp * 8;
            float4 x0 = *reinterpret_cast<const float4*>(xp);
            float4 x1 = *reinterpret_cast<const float4*>(xp + 4);
            half8 h;
            h[0] = (_Float16)x0.x; h[1] = (_Float16)x0.y;
            h[2] = (_Float16)x0.z; h[3] = (_Float16)x0.w;
            h[4] = (_Float16)x1.x; h[5] = (_Float16)x1.y;
            h[6] = (_Float16)x1.z; h[7] = (_Float16)x1.w;
            afrag[c] = h;
        }

        floatx4 acc[4];
        #pragma unroll
        for (int jg = 0; jg < 4; ++jg) {
            floatx4 a = {0.0f, 0.0f, 0.0f, 0.0f};
            a = __builtin_amdgcn_mfma_f32_16x16x32_f16(afrag[0], bfrag[0][jg], a, 0, 0, 0);
            a = __builtin_amdgcn_mfma_f32_16x16x32_f16(afrag[1], bfrag[1][jg], a, 0, 0, 0);
            acc[jg] = a;
        }

        // store: lane l reg r -> node base+(l>>4)*4+r, feature jg*16 + (l&15)
        #pragma unroll
        for (int jg = 0; jg < 4; ++jg) {
            #pragma unroll
            for (int r = 0; r < 4; ++r) {
                const int node = base + kgrp * 4 + r;
                Yh[(size_t)node * 64 + jg * 16 + row16] = __float2half(acc[jg][r]);
            }
        }
    } else {
        __shared__ int h[NBC];
        const int b = blockIdx.x - MFB;
        if (threadIdx.x < NBC) h[threadIdx.x] = 0;
        __syncthreads();
        const int lo = b * TILE;
        const int hi = min(lo + TILE, N_EDGES);
        for (int e = lo + threadIdx.x; e < hi; e += 256)
            atomicAdd(&h[edges[e] >> SHC], 1);
        __syncthreads();
        if (threadIdx.x < NBC) {
            int v = h[threadIdx.x];
            if (v) atomicAdd(&bcntC[threadIdx.x], v);
        }
    }
}

// ---------------------------------------------------------------------------
// K2 reservation scatter (round-7 proven): 196 blocks x 1024 thr, 8 e/thread.
// ---------------------------------------------------------------------------
__global__ __launch_bounds__(1024) void s_scatter(const int* __restrict__ edges,
                                                  const int* __restrict__ bcntC,
                                                  int* __restrict__ cursorDelta,
                                                  int* __restrict__ bbaseC,
                                                  int* __restrict__ packed)
{
    __shared__ int s[256];
    __shared__ int baseC[NBC];
    __shared__ int h[NBC];
    __shared__ int chunk[NBC];
    const int t = threadIdx.x;

    int v = 0;
    if (t < 256) { v = (t < NBC) ? bcntC[t] : 0; s[t] = v; }
    __syncthreads();
    for (int o = 1; o < 256; o <<= 1) {
        int u = (t < 256 && t >= o) ? s[t - o] : 0;
        __syncthreads();
        if (t < 256) s[t] += u;
        __syncthreads();
    }
    if (t < NBC) {
        int e = s[t] - v;
        baseC[t] = e;
        h[t] = 0;
        if (blockIdx.x == 0) bbaseC[t] = e;
    }
    __syncthreads();

    const int lo = blockIdx.x * TILE2;
    int myd[8];
    #pragma unroll
    for (int k = 0; k < 8; ++k) {
        int e = lo + k * 1024 + t;
        myd[k] = (e < N_EDGES) ? edges[e] : -1;
        if (myd[k] >= 0) atomicAdd(&h[myd[k] >> SHC], 1);
    }
    __syncthreads();

    if (t < NBC) {
        int c = h[t];
        chunk[t] = c ? (baseC[t] + atomicAdd(&cursorDelta[t], c)) : 0;
        h[t] = 0;                        // reuse as local cursor
    }
    __syncthreads();

    #pragma unroll
    for (int k = 0; k < 8; ++k) {
        if (myd[k] >= 0) {
            int e = lo + k * 1024 + t;
            int src = edges[N_EDGES + e];
            int j = myd[k] >> SHC;
            int r = atomicAdd(&h[j], 1);
            packed[chunk[j] + r] = (src << SHC) | (myd[k] & (BSZC - 1));
        }
    }
}

// ---------------------------------------------------------------------------
// K3 csr512 (round-11 proven): one block per coarse region (196 x 1024 thr).
// ---------------------------------------------------------------------------
__global__ __launch_bounds__(1024) void csr512(const int* __restrict__ packed,
                                               const int* __restrict__ bbaseC,
                                               const int* __restrict__ bcntC,
                                               int* __restrict__ offsets,
                                               int* __restrict__ deg,
                                               int* __restrict__ srt)
{
    __shared__ int h2[BSZC];
    __shared__ int cur2[BSZC];
    __shared__ int s[BSZC];
    const int b = blockIdx.x;
    const int t = threadIdx.x;
    const int start = bbaseC[b];
    const int cnt   = bcntC[b];

    if (t < BSZC) h2[t] = 0;
    __syncthreads();
    for (int i = t; i < cnt; i += 1024)
        atomicAdd(&h2[packed[start + i] & (BSZC - 1)], 1);
    __syncthreads();

    if (t < BSZC) s[t] = h2[t];
    __syncthreads();
    for (int o = 1; o < BSZC; o <<= 1) {
        int u = (t < BSZC && t >= o) ? s[t - o] : 0;
        __syncthreads();
        if (t < BSZC) s[t] += u;
        __syncthreads();
    }
    if (t < BSZC) {
        int excl = s[t] - h2[t];
        int node = (b << SHC) + t;
        if (node < N_NODES) { offsets[node] = start + excl; deg[node] = h2[t]; }
        cur2[t] = excl;
    }
    __syncthreads();
    for (int i = t; i < cnt; i += 1024) {
        int p = packed[start + i];
        int r = atomicAdd(&cur2[p & (BSZC - 1)], 1);
        srt[start + r] = p >> SHC;
    }
}

// ---------------------------------------------------------------------------
// K4 gather (round-10 proven): one wave per TWO nodes (interleaved).
// 8x8-lane groups; one wave64 dwordx4 fetches 8 fp16 rows; fp32 accumulate;
// shfl_xor(8,16,32) combine; scale+bias; fp32 out.
// ---------------------------------------------------------------------------
__device__ __forceinline__ void addrow(float* acc, uint4 u)
{
    const __half2* h = reinterpret_cast<const __half2*>(&u);
    #pragma unroll
    for (int k = 0; k < 4; ++k) {
        float2 f = __half22float2(h[k]);
        acc[2 * k]     += f.x;
        acc[2 * k + 1] += f.y;
    }
}

__global__ __launch_bounds__(256) void gather_h(
    const __half* __restrict__ Yh,
    const int* __restrict__ offsets,
    const int* __restrict__ deg,
    const int* __restrict__ srt,
    const float* __restrict__ bias,
    float* __restrict__ out)
{
    const int wid  = threadIdx.x >> 6;
    const int lane = threadIdx.x & 63;
    const int g    = lane >> 3;          // edge slot within octet
    const int sub  = lane & 7;           // 16B chunk within 128B row
    const int n0   = blockIdx.x * 8 + wid * 2;
    const int n1   = n0 + 1;
    if (n0 >= N_NODES) return;           // wave-uniform
    const bool has1 = (n1 < N_NODES);

    const int st0 = offsets[n0];
    const int c0  = deg[n0];
    int st1 = 0, c1 = 0;
    if (has1) { st1 = offsets[n1]; c1 = deg[n1]; }

    float a0[8], a1[8];
    #pragma unroll
    for (int j = 0; j < 8; ++j) { a0[j] = 0.0f; a1[j] = 0.0f; }

    if (g == 0) {                        // self loops
        uint4 u0 = *reinterpret_cast<const uint4*>(Yh + (size_t)n0 * D + sub * 8);
        addrow(a0, u0);
        if (has1) {
            uint4 u1 = *reinterpret_cast<const uint4*>(Yh + (size_t)n1 * D + sub * 8);
            addrow(a1, u1);
        }
    }

    // interleaved main: one row-load per node per step -> 2+ loads in flight
    const int m = min(c0 & ~7, c1 & ~7);
    int e = 0;
    for (; e < m; e += 8) {
        int s0 = srt[st0 + e + g];
        int s1 = srt[st1 + e + g];
        uint4 u0 = *reinterpret_cast<const uint4*>(Yh + (size_t)s0 * D + sub * 8);
        uint4 u1 = *reinterpret_cast<const uint4*>(Yh + (size_t)s1 * D + sub * 8);
        addrow(a0, u0);
        addrow(a1, u1);
    }

    // drain node0
    int e0 = e;
    for (; e0 + 16 <= c0; e0 += 16) {
        int s0 = srt[st0 + e0 + g];
        int s1 = srt[st0 + e0 + 8 + g];
        uint4 u0 = *reinterpret_cast<const uint4*>(Yh + (size_t)s0 * D + sub * 8);
        uint4 u1 = *reinterpret_cast<const uint4*>(Yh + (size_t)s1 * D + sub * 8);
        addrow(a0, u0);
        addrow(a0, u1);
    }
    if (e0 + 8 <= c0) {
        int s0 = srt[st0 + e0 + g];
        uint4 u0 = *reinterpret_cast<const uint4*>(Yh + (size_t)s0 * D + sub * 8);
        addrow(a0, u0);
        e0 += 8;
    }
    if (e0 + g < c0) {
        int s0 = srt[st0 + e0 + g];
        uint4 u0 = *reinterpret_cast<const uint4*>(Yh + (size_t)s0 * D + sub * 8);
        addrow(a0, u0);
    }

    // drain node1
    if (has1) {
        int e1 = e;
        for (; e1 + 16 <= c1; e1 += 16) {
            int s0 = srt[st1 + e1 + g];
            int s1 = srt[st1 + e1 + 8 + g];
            uint4 u0 = *reinterpret_cast<const uint4*>(Yh + (size_t)s0 * D + sub * 8);
            uint4 u1 = *reinterpret_cast<const uint4*>(Yh + (size_t)s1 * D + sub * 8);
            addrow(a1, u0);
            addrow(a1, u1);
        }
        if (e1 + 8 <= c1) {
            int s0 = srt[st1 + e1 + g];
            uint4 u0 = *reinterpret_cast<const uint4*>(Yh + (size_t)s0 * D + sub * 8);
            addrow(a1, u0);
            e1 += 8;
        }
        if (e1 + g < c1) {
            int s0 = srt[st1 + e1 + g];
            uint4 u0 = *reinterpret_cast<const uint4*>(Yh + (size_t)s0 * D + sub * 8);
            addrow(a1, u0);
        }
    }

    #pragma unroll
    for (int j = 0; j < 8; ++j) {
        a0[j] += __shfl_xor(a0[j], 8, 64);
        a0[j] += __shfl_xor(a0[j], 16, 64);
        a0[j] += __shfl_xor(a0[j], 32, 64);
        a1[j] += __shfl_xor(a1[j], 8, 64);
        a1[j] += __shfl_xor(a1[j], 16, 64);
        a1[j] += __shfl_xor(a1[j], 32, 64);
    }

    if (g == 0) {
        const float4 b0 = *reinterpret_cast<const float4*>(bias + sub * 8);
        const float4 b1 = *reinterpret_cast<const float4*>(bias + sub * 8 + 4);
        {
            const float sc = rsqrtf((float)c0 + 1.0f);
            float4 r0, r1;
            r0.x = a0[0] * sc + b0.x;  r0.y = a0[1] * sc + b0.y;
            r0.z = a0[2] * sc + b0.z;  r0.w = a0[3] * sc + b0.w;
            r1.x = a0[4] * sc + b1.x;  r1.y = a0[5] * sc + b1.y;
            r1.z = a0[6] * sc + b1.z;  r1.w = a0[7] * sc + b1.w;
            *reinterpret_cast<float4*>(out + (size_t)n0 * D + sub * 8)     = r0;
            *reinterpret_cast<float4*>(out + (size_t)n0 * D + sub * 8 + 4) = r1;
        }
        if (has1) {
            const float sc = rsqrtf((float)c1 + 1.0f);
            float4 r0, r1;
            r0.x = a1[0] * sc + b0.x;  r0.y = a1[1] * sc + b0.y;
            r0.z = a1[2] * sc + b0.z;  r0.w = a1[3] * sc + b0.w;
            r1.x = a1[4] * sc + b1.x;  r1.y = a1[5] * sc + b1.y;
            r1.z = a1[6] * sc + b1.z;  r1.w = a1[7] * sc + b1.w;
            *reinterpret_cast<float4*>(out + (size_t)n1 * D + sub * 8)     = r0;
            *reinterpret_cast<float4*>(out + (size_t)n1 * D + sub * 8 + 4) = r1;
        }
    }
}

// ---------------------------------------------------------------------------
// mid tier: round-0 proven pipeline (fp32 throughout)
// ---------------------------------------------------------------------------

__global__ __launch_bounds__(256) void linear_kernel(
    const float* __restrict__ vertices,
    const float* __restrict__ weight,
    float* __restrict__ Y)
{
    __shared__ float rowbuf[4][64];
    const int wid  = threadIdx.x >> 6;
    const int lane = threadIdx.x & 63;
    float w[64];
    #pragma unroll
    for (int f = 0; f < 64; ++f) w[f] = weight[lane * 64 + f];
    const int nodesPerIter = gridDim.x * 4;
    for (int base = blockIdx.x * 4; base < N_NODES; base += nodesPerIter) {
        const int node = base + wid;
        float a = 0.0f;
        if (node < N_NODES) a = vertices[(size_t)node * D + lane];
        rowbuf[wid][lane] = a;
        __syncthreads();
        float acc = 0.0f;
        #pragma unroll
        for (int f = 0; f < 64; ++f)
            acc += rowbuf[wid][f] * w[f];
        if (node < N_NODES) Y[(size_t)node * D + lane] = acc;
        __syncthreads();
    }
}

__global__ __launch_bounds__(256) void gather_f32(
    const float* __restrict__ Y,
    const int* __restrict__ offsets,
    const int* __restrict__ deg,
    const int* __restrict__ sortedSrc,
    const float* __restrict__ bias,
    float* __restrict__ out)
{
    const int wid  = threadIdx.x >> 6;
    const int lane = threadIdx.x & 63;
    const int g    = lane >> 4;
    const int sub  = lane & 15;
    const int node = blockIdx.x * 4 + wid;
    if (node >= N_NODES) return;

    const int start = offsets[node];
    const int cnt   = deg[node];

    float4 acc;
    if (g == 0) {
        acc = *reinterpret_cast<const float4*>(Y + (size_t)node * D + (sub << 2));
    } else {
        acc.x = 0.0f; acc.y = 0.0f; acc.z = 0.0f; acc.w = 0.0f;
    }

    int e = 0;
    for (; e + 8 <= cnt; e += 8) {
        int s0 = sortedSrc[start + e + g];
        int s1 = sortedSrc[start + e + 4 + g];
        const float4 a0 = *reinterpret_cast<const float4*>(Y + (size_t)s0 * D + (sub << 2));
        const float4 a1 = *reinterpret_cast<const float4*>(Y + (size_t)s1 * D + (sub << 2));
        acc.x += a0.x; acc.y += a0.y; acc.z += a0.z; acc.w += a0.w;
        acc.x += a1.x; acc.y += a1.y; acc.z += a1.z; acc.w += a1.w;
    }
    if (e + 4 <= cnt) {
        int s0 = sortedSrc[start + e + g];
        const float4 a0 = *reinterpret_cast<const float4*>(Y + (size_t)s0 * D + (sub << 2));
        acc.x += a0.x; acc.y += a0.y; acc.z += a0.z; acc.w += a0.w;
        e += 4;
    }
    if (e + g < cnt) {
        int s0 = sortedSrc[start + e + g];
        const float4 a0 = *reinterpret_cast<const float4*>(Y + (size_t)s0 * D + (sub << 2));
        acc.x += a0.x; acc.y += a0.y; acc.z += a0.z; acc.w += a0.w;
    }

    acc.x += __shfl_xor(acc.x, 16, 64);
    acc.y += __shfl_xor(acc.y, 16, 64);
    acc.z += __shfl_xor(acc.z, 16, 64);
    acc.w += __shfl_xor(acc.w, 16, 64);
    acc.x += __shfl_xor(acc.x, 32, 64);
    acc.y += __shfl_xor(acc.y, 32, 64);
    acc.z += __shfl_xor(acc.z, 32, 64);
    acc.w += __shfl_xor(acc.w, 32, 64);

    if (lane < 16) {
        const float sc = rsqrtf((float)cnt + 1.0f);
        const float4 b4 = *reinterpret_cast<const float4*>(bias + (sub << 2));
        float4 r;
        r.x = acc.x * sc + b4.x;
        r.y = acc.y * sc + b4.y;
        r.z = acc.z * sc + b4.z;
        r.w = acc.w * sc + b4.w;
        *reinterpret_cast<float4*>(out + (size_t)node * D + (sub << 2)) = r;
    }
}

__global__ __launch_bounds__(256) void hist_kernel(const int* __restrict__ edges,
                                                   int* __restrict__ deg)
{
    int e = blockIdx.x * 256 + threadIdx.x;
    if (e < N_EDGES) atomicAdd(&deg[edges[e]], 1);
}

__global__ __launch_bounds__(256) void scan_part(const int* __restrict__ deg,
                                                 int* __restrict__ partial)
{
    int t = threadIdx.x;
    int base = blockIdx.x * SCAN_CHUNK + t * 4;
    int s = 0;
    #pragma unroll
    for (int k = 0; k < 4; ++k) { int i = base + k; if (i < N_NODES) s += deg[i]; }
    int lane = t & 63, wid = t >> 6;
    #pragma unroll
    for (int off = 32; off; off >>= 1) s += __shfl_down(s, off, 64);
    __shared__ int red[4];
    if (lane == 0) red[wid] = s;
    __syncthreads();
    if (t == 0) partial[blockIdx.x] = red[0] + red[1] + red[2] + red[3];
}

__global__ void scan_small(int* partial) {
    int lane = threadIdx.x;
    int v0 = (lane < NCHUNK) ? partial[lane] : 0;
    int v1 = (64 + lane < NCHUNK) ? partial[64 + lane] : 0;
    int i0 = waveInclScan(v0, lane);
    int tot0 = __shfl(i0, 63, 64);
    int i1 = waveInclScan(v1, lane) + tot0;
    if (lane < NCHUNK) partial[lane] = i0 - v0;
    if (64 + lane < NCHUNK) partial[64 + lane] = i1 - v1;
}

__global__ __launch_bounds__(256) void scan_final(const int* __restrict__ deg,
                                                  const int* __restrict__ partial,
                                                  int* __restrict__ offsets,
                                                  int* __restrict__ cursor)
{
    int t = threadIdx.x;
    int base = blockIdx.x * SCAN_CHUNK + t * 4;
    int d[4]; int s = 0;
    #pragma unroll
    for (int k = 0; k < 4; ++k) { int i = base + k; d[k] = (i < N_NODES) ? deg[i] : 0; s += d[k]; }
    __shared__ int sd[256];
    sd[t] = s; __syncthreads();
    #pragma unroll
    for (int off = 1; off < 256; off <<= 1) {
        int v = (t >= off) ? sd[t - off] : 0;
        __syncthreads();
        sd[t] += v;
        __syncthreads();
    }
    int excl = sd[t] - s + partial[blockIdx.x];
    #pragma unroll
    for (int k = 0; k < 4; ++k) {
        int i = base + k;
        if (i < N_NODES) { offsets[i] = excl; cursor[i] = excl; excl += d[k]; }
    }
}

__global__ __launch_bounds__(256) void scatter_idx(const int* __restrict__ edges,
                                                   int* __restrict__ cursor,
                                                   int* __restrict__ sortedSrc)
{
    int e = blockIdx.x * 256 + threadIdx.x;
    if (e >= N_EDGES) return;
    int dst = edges[e];
    int src = edges[N_EDGES + e];
    int pos = atomicAdd(&cursor[dst], 1);
    sortedSrc[pos] = src;
}

// ---------------------------------------------------------------------------
// last-resort fallback (round-1, proven)
// ---------------------------------------------------------------------------

__global__ __launch_bounds__(256) void fb_scatter(
    const float* __restrict__ vertices, const int* __restrict__ edges,
    float* __restrict__ agg, float* __restrict__ degF)
{
    long long tid = (long long)blockIdx.x * 256 + threadIdx.x;
    int lane = threadIdx.x & 63;
    long long e = tid >> 6;
    if (e >= N_EDGES) return;
    int dst = edges[e];
    int src = edges[N_EDGES + e];
    atomicAdd(&agg[(size_t)dst * D + lane], vertices[(size_t)src * D + lane]);
    if (lane == 0) atomicAdd(&degF[dst], 1.0f);
}

__global__ __launch_bounds__(256) void fb_finish(
    const float* __restrict__ vertices, const float* __restrict__ weight,
    const float* __restrict__ bias, const float* __restrict__ degF,
    float* __restrict__ out)
{
    __shared__ float rowbuf[4][64];
    const int wid  = threadIdx.x >> 6;
    const int lane = threadIdx.x & 63;
    float w[64];
    #pragma unroll
    for (int f = 0; f < 64; ++f) w[f] = weight[lane * 64 + f];
    const float b = bias[lane];
    const int nodesPerIter = gridDim.x * 4;
    for (int base = blockIdx.x * 4; base < N_NODES; base += nodesPerIter) {
        const int node = base + wid;
        float a = 0.0f;
        if (node < N_NODES) {
            const float scale = rsqrtf(degF[node] + 1.0f);
            a = (out[(size_t)node * D + lane] + vertices[(size_t)node * D + lane]) * scale;
        }
        rowbuf[wid][lane] = a;
        __syncthreads();
        float acc = b;
        #pragma unroll
        for (int f = 0; f < 64; ++f) acc += rowbuf[wid][f] * w[f];
        if (node < N_NODES) out[(size_t)node * D + lane] = acc;
        __syncthreads();
    }
}

extern "C" void kernel_launch(void* const* d_in, const int* in_sizes, int n_in,
                              void* d_out, int out_size, void* d_ws, size_t ws_size,
                              hipStream_t stream) {
    const float* vertices = (const float*)d_in[0];
    const int*   edges    = (const int*)d_in[1];
    const float* weight   = (const float*)d_in[2];
    const float* bias     = (const float*)d_in[3];
    float* out = (float*)d_out;

    const int threads = 256;
    const int edgeBlocks = (N_EDGES + threads - 1) / threads;

    // --- fast layout: Yh(fp16) | bcntC | cursorDelta | bbaseC | offs | deg | packed | srt
    {
        __half* Yh         = (__half*)d_ws;
        int*   bcntC       = (int*)(Yh + (size_t)N_NODES * D);
        int*   cursorDelta = bcntC + NBC;
        int*   bbaseC      = cursorDelta + NBC;
        int*   offs        = bbaseC + NBC;
        int*   deg         = offs + N_NODES;
        int*   packed      = deg + N_NODES;
        int*   srt         = packed + N_EDGES;
        size_t needed      = (size_t)((char*)(srt + N_EDGES) - (char*)d_ws);
        if (ws_size >= needed) {
            (void)hipMemsetAsync(bcntC, 0, sizeof(int) * 2 * NBC, stream);  // bcntC + cursorDelta
            mfma_hist<<<MFB + SPLITB, threads, 0, stream>>>(vertices, weight, Yh, edges, bcntC);
            s_scatter<<<NBLK2, 1024, 0, stream>>>(edges, bcntC, cursorDelta, bbaseC, packed);
            csr512<<<NBC, 1024, 0, stream>>>(packed, bbaseC, bcntC, offs, deg, srt);
            gather_h<<<(N_NODES + 7) / 8, threads, 0, stream>>>(Yh, offs, deg, srt, bias, out);
            return;
        }
    }

    // --- mid layout (round-0 proven): Y | deg | offsets | cursor | partial[128] | srt
    {
        float* Y       = (float*)d_ws;
        int*   deg     = (int*)(Y + (size_t)N_NODES * D);
        int*   offs    = deg + N_NODES;
        int*   cursor  = offs + N_NODES;
        int*   partial = cursor + N_NODES;
        int*   srt     = partial + 128;
        size_t needed  = (size_t)((char*)(srt + N_EDGES) - (char*)d_ws);
        if (ws_size >= needed) {
            (void)hipMemsetAsync(deg, 0, sizeof(int) * N_NODES, stream);
            linear_kernel<<<1024, threads, 0, stream>>>(vertices, weight, Y);
            hist_kernel<<<edgeBlocks, threads, 0, stream>>>(edges, deg);
            scan_part<<<NCHUNK, threads, 0, stream>>>(deg, partial);
            scan_small<<<1, 64, 0, stream>>>(partial);
            scan_final<<<NCHUNK, threads, 0, stream>>>(deg, partial, offs, cursor);
            scatter_idx<<<edgeBlocks, threads, 0, stream>>>(edges, cursor, srt);
            gather_f32<<<(N_NODES + 3) / 4, threads, 0, stream>>>(Y, offs, deg, srt, bias, out);
            return;
        }
    }

    // --- last resort
    {
        float* degF = (float*)d_ws;
        (void)hipMemsetAsync(out, 0, sizeof(float) * (size_t)N_NODES * D, stream);
        (void)hipMemsetAsync(degF, 0, sizeof(float) * N_NODES, stream);
        const long long totalScatter = (long long)N_EDGES * 64;
        fb_scatter<<<(int)((totalScatter + threads - 1) / threads), threads, 0, stream>>>(
            vertices, edges, out, degF);
        fb_finish<<<1024, threads, 0, stream>>>(vertices, weight, bias, degF, out);
    }
}